// Round 15
// baseline (488.957 us; speedup 1.0000x reference)
//
#include <hip/hip_runtime.h>
#include <hip/hip_cooperative_groups.h>

namespace cg = cooperative_groups;

// SparseProductLayer:  out = x @ (M0*M1*M2)^T + bias
// Pipeline: ONE cooperative prep kernel (zero+xconv | hist | scan | scatter |
// mcbuild, grid.sync between phases; 1024 blocks = 4/CU co-resident) ->
// MFMA GEMM (r14 core: BM=128,BN=256,BK=64, 3-slot ring, vmcnt(6), pinned
// frag dbuf, chunk^row&7 swizzle, setprio, XCD-chunked block swizzle).

#define BATCH 4096
#define DIM   2048
#define NNZc  16384
#define NT    256

typedef short bf16x8 __attribute__((ext_vector_type(8)));
typedef float f32x4  __attribute__((ext_vector_type(4)));

__device__ __forceinline__ unsigned short f2bf(float f) {
    unsigned u = __float_as_uint(f);
    unsigned r = (u + 0x7fffu + ((u >> 16) & 1u)) >> 16;   // RNE
    return (unsigned short)r;
}

__device__ __forceinline__ void gload16(const void* g, void* l) {
    __builtin_amdgcn_global_load_lds((const __attribute__((address_space(1))) void*)g,
                                     (__attribute__((address_space(3))) void*)l, 16, 0, 0);
}

// ---- cooperative prep: zero+xconv -> hist -> scan -> scatter -> mcbuild ----
#define RPB  2
#define PCAP 2048
#define PREP_BLOCKS 1024

__global__ __launch_bounds__(256, 4) void prep_kernel(
        const float* __restrict__ x, unsigned short* __restrict__ Xb,
        const int* __restrict__ rws0, const int* __restrict__ cls0, const float* __restrict__ vls0,
        const int* __restrict__ rws1, const int* __restrict__ cls1, const float* __restrict__ vls1,
        const int* __restrict__ rws2, const int* __restrict__ cls2, const float* __restrict__ vls2,
        int* __restrict__ curb, int* __restrict__ offb,
        int* __restrict__ colb, float* __restrict__ valb,
        unsigned short* __restrict__ Mc) {
    cg::grid_group grid = cg::this_grid();
    const int bid  = blockIdx.x;
    const int tid  = threadIdx.x;
    const int gtid = bid * NT + tid;

    __shared__ char shbuf[32776];     // mcbuild: acc 16K | pk 8K | pw 8K | npairs

    // ---- phase 0: zero counters + x -> bf16 (independent work) ----
    if (gtid < 3 * DIM) curb[gtid] = 0;
    #pragma unroll
    for (int u = 0; u < 4; ++u) {
        size_t i = ((size_t)u * (PREP_BLOCKS * NT) + gtid) * 8;
        float4 a = *(const float4*)(x + i);
        float4 b = *(const float4*)(x + i + 4);
        unsigned short o[8] = {f2bf(a.x), f2bf(a.y), f2bf(a.z), f2bf(a.w),
                               f2bf(b.x), f2bf(b.y), f2bf(b.z), f2bf(b.w)};
        *(ulonglong2*)(Xb + i) = *(ulonglong2*)o;
    }
    grid.sync();

    // ---- phase 1: histogram ----
    if (gtid < 3 * NNZc) {
        int m = gtid >> 14, i = gtid & (NNZc - 1);
        const int* rp = (m == 0) ? rws0 : (m == 1) ? rws1 : rws2;
        atomicAdd(&curb[m * DIM + rp[i]], 1);
    }
    grid.sync();

    // ---- phase 2: exclusive scan (blocks 0..2, shuffle scan) ----
    if (bid < 3) {
        int* cur = curb + bid * DIM;
        int* off = offb + bid * 2052;
        int* wsum = (int*)shbuf;
        int c[8]; int s = 0;
        #pragma unroll
        for (int i = 0; i < 8; ++i) { c[i] = cur[tid * 8 + i]; s += c[i]; }
        int l = tid & 63, wv = tid >> 6;
        int v = s;
        #pragma unroll
        for (int d = 1; d < 64; d <<= 1) {
            int u = __shfl_up(v, d, 64);
            if (l >= d) v += u;
        }
        if (l == 63) wsum[wv] = v;
        __syncthreads();
        int wbase = 0;
        for (int i = 0; i < wv; ++i) wbase += wsum[i];
        int base = wbase + v - s;
        #pragma unroll
        for (int i = 0; i < 8; ++i) {
            int idx = tid * 8 + i;
            off[idx] = base; cur[idx] = base; base += c[i];
        }
        if (tid == 0) off[DIM] = NNZc;
    }
    grid.sync();

    // ---- phase 3: scatter ----
    if (gtid < 3 * NNZc) {
        int m = gtid >> 14, i = gtid & (NNZc - 1);
        const int*   rp = (m == 0) ? rws0 : (m == 1) ? rws1 : rws2;
        const int*   cp = (m == 0) ? cls0 : (m == 1) ? cls1 : cls2;
        const float* vp = (m == 0) ? vls0 : (m == 1) ? vls1 : vls2;
        int slot = atomicAdd(&curb[m * DIM + rp[i]], 1);
        colb[m * NNZc + slot] = cp[i];
        valb[m * NNZc + slot] = vp[i];
    }
    grid.sync();

    // ---- phase 4: mcbuild (block b -> Mc rows 2b, 2b+1) ----
    {
        const int* off0 = offb;            const int* off1 = offb + 2052; const int* off2 = offb + 4104;
        const int* col0 = colb;            const int* col1 = colb + NNZc; const int* col2 = colb + 2 * NNZc;
        const float* val0 = valb;          const float* val1 = valb + NNZc; const float* val2 = valb + 2 * NNZc;

        float* acc   = (float*)shbuf;                 // RPB*DIM
        int*   pk    = (int*)(shbuf + 16384);         // PCAP
        float* pw    = (float*)(shbuf + 24576);       // PCAP
        int*   npp   = (int*)(shbuf + 32768);

        const int row0 = bid * RPB;

        __syncthreads();    // shbuf was used by scan on blocks 0..2
        f32x4* az = (f32x4*)acc;
        #pragma unroll
        for (int j = tid; j < RPB * DIM / 4; j += NT) az[j] = (f32x4){0.f, 0.f, 0.f, 0.f};
        if (tid == 0) *npp = 0;
        __syncthreads();

        #pragma unroll
        for (int k = 0; k < RPB; ++k) {
            int b = off0[row0 + k], e = off0[row0 + k + 1];
            for (int i = b + tid; i < e; i += NT) {
                int   c0 = col0[i];
                float v0 = val0[i];
                int b1 = off1[c0], e1 = off1[c0 + 1];
                for (int j = b1; j < e1; ++j) {
                    float w = v0 * val1[j];
                    int   c1 = col1[j];
                    int slot = atomicAdd(npp, 1);
                    if (slot < PCAP) { pk[slot] = (k << 16) | c1; pw[slot] = w; }
                    else {
                        int b2 = off2[c1], e2 = off2[c1 + 1];
                        for (int q = b2; q < e2; ++q)
                            atomicAdd(&acc[k * DIM + col2[q]], w * val2[q]);
                    }
                }
            }
        }
        __syncthreads();

        int np = min(*npp, PCAP);
        for (int p = tid; p < np; p += NT) {
            int   k  = pk[p] >> 16, c1 = pk[p] & 0xffff;
            float w  = pw[p];
            int b2 = off2[c1], e2 = off2[c1 + 1];
            for (int q = b2; q < e2; ++q)
                atomicAdd(&acc[k * DIM + col2[q]], w * val2[q]);
        }
        __syncthreads();

        #pragma unroll
        for (int k = 0; k < RPB; ++k) {
            unsigned short o[8];
            #pragma unroll
            for (int jj = 0; jj < 8; ++jj) o[jj] = f2bf(acc[k * DIM + tid * 8 + jj]);
            *(ulonglong2*)(Mc + (size_t)(row0 + k) * DIM + tid * 8) = *(ulonglong2*)o;
        }
    }
}

// ---- GEMM: C = Xb(4096x2048) @ Mc^T + bias (r14 core, unchanged) ----
#define BM 128
#define BN 256
#define BK 64
#define NS (DIM / BK)                   // 32
#define A_SL (BM * BK * 2)              // 16384
#define B_SL (BN * BK * 2)              // 32768
#define SLOT (A_SL + B_SL)              // 49152
#define GEMM_LDS (3 * SLOT)             // 147456

__global__ __launch_bounds__(512, 2) void gemm8(
        const unsigned short* __restrict__ A,   // Xb [4096][2048]
        const unsigned short* __restrict__ Bm,  // Mc [2048][2048]
        const float* __restrict__ bias,
        float* __restrict__ C) {
    extern __shared__ char smem[];
    const int tid = threadIdx.x;
    const int l = tid & 63, w = tid >> 6;
    const int wm = w & 1, wn = w >> 1;          // 2M x 4N wave grid, tile 64x64

    // XCD-chunked swizzle: xcd k=(bid&7) owns an 8y x 4x region
    const int bid = blockIdx.x;
    const int k = bid & 7, c = bid >> 3;
    const int tileM = ((k >> 1) * 8 + (c >> 2)) * BM;
    const int tileN = ((k & 1) * 4 + (c & 3)) * BN;

    const int r8   = l >> 3;
    const int clog = (l & 7) ^ r8;
    const unsigned short* aS0 = A  + (size_t)(tileM + 8 * w + r8) * DIM + clog * 8;
    const unsigned short* aS1 = aS0 + (size_t)64 * DIM;
    const unsigned short* bS0 = Bm + (size_t)(tileN + 32 * w + r8) * DIM + clog * 8;

#define STAGE(z, s) do {                                                   \
    gload16(aS0 +                (size_t)(s) * BK, (z) + w * 1024);        \
    gload16(aS1 +                (size_t)(s) * BK, (z) + 8192 + w * 1024); \
    gload16(bS0 +                (size_t)(s) * BK, (z) + A_SL + w * 4096);        \
    gload16(bS0 +  8 * DIM +     (size_t)(s) * BK, (z) + A_SL + w * 4096 + 1024); \
    gload16(bS0 + 16 * DIM +     (size_t)(s) * BK, (z) + A_SL + w * 4096 + 2048); \
    gload16(bS0 + 24 * DIM +     (size_t)(s) * BK, (z) + A_SL + w * 4096 + 3072); \
} while (0)

    const int rbyte = (l & 15) * 128;
    const int c0 = (((l >> 4)    ) ^ (l & 7)) * 16;   // ks=0
    const int c1 = (((l >> 4) + 4) ^ (l & 7)) * 16;   // ks=1

#define LOADFRAGS(z, A0, A1, B0, B1) do {                            \
    const char* _ab = (z) + wm * 8192 + rbyte;                       \
    A0[0] = *(const bf16x8*)(_ab + 0 * 2048 + c0);                   \
    A1[0] = *(const bf16x8*)(_ab + 0 * 2048 + c1);                   \
    A0[1] = *(const bf16x8*)(_ab + 1 * 2048 + c0);                   \
    A1[1] = *(const bf16x8*)(_ab + 1 * 2048 + c1);                   \
    A0[2] = *(const bf16x8*)(_ab + 2 * 2048 + c0);                   \
    A1[2] = *(const bf16x8*)(_ab + 2 * 2048 + c1);                   \
    A0[3] = *(const bf16x8*)(_ab + 3 * 2048 + c0);                   \
    A1[3] = *(const bf16x8*)(_ab + 3 * 2048 + c1);                   \
    const char* _bb = (z) + A_SL + wn * 8192 + rbyte;                \
    B0[0] = *(const bf16x8*)(_bb + 0 * 2048 + c0);                   \
    B1[0] = *(const bf16x8*)(_bb + 0 * 2048 + c1);                   \
    B0[1] = *(const bf16x8*)(_bb + 1 * 2048 + c0);                   \
    B1[1] = *(const bf16x8*)(_bb + 1 * 2048 + c1);                   \
    B0[2] = *(const bf16x8*)(_bb + 2 * 2048 + c0);                   \
    B1[2] = *(const bf16x8*)(_bb + 2 * 2048 + c1);                   \
    B0[3] = *(const bf16x8*)(_bb + 3 * 2048 + c0);                   \
    B1[3] = *(const bf16x8*)(_bb + 3 * 2048 + c1);                   \
} while (0)

#define PIN(X) asm volatile("" : "+v"(X[0]), "+v"(X[1]), "+v"(X[2]), "+v"(X[3]))

#define MFMA32(A0, A1, B0, B1) do {                                                    \
    _Pragma("unroll")                                                                  \
    for (int _q = 0; _q < 4; ++_q)                                                     \
        _Pragma("unroll")                                                              \
        for (int _j = 0; _j < 4; ++_j) {                                               \
            acc[_q][_j] = __builtin_amdgcn_mfma_f32_16x16x32_bf16(A0[_q], B0[_j],      \
                                                                  acc[_q][_j], 0,0,0); \
            acc[_q][_j] = __builtin_amdgcn_mfma_f32_16x16x32_bf16(A1[_q], B1[_j],      \
                                                                  acc[_q][_j], 0,0,0); \
        }                                                                              \
} while (0)

    bf16x8 Ae0[4], Ae1[4], Be0[4], Be1[4];
    bf16x8 Ao0[4], Ao1[4], Bo0[4], Bo1[4];
    f32x4 acc[4][4] = {};

    char* p0 = smem;
    char* p1 = smem + SLOT;
    char* p2 = smem + 2 * SLOT;

    STAGE(p0, 0);
    STAGE(p1, 1);
    asm volatile("s_waitcnt vmcnt(6)" ::: "memory");
    __builtin_amdgcn_sched_barrier(0);
    __builtin_amdgcn_s_barrier();
    LOADFRAGS(p0, Ae0, Ae1, Be0, Be1);
    PIN(Ae0); PIN(Ae1); PIN(Be0); PIN(Be1);
    asm volatile("s_waitcnt lgkmcnt(0)" ::: "memory");
    __builtin_amdgcn_sched_barrier(0);

#define BODY(CURA0, CURA1, CURB0, CURB1, NXTA0, NXTA1, NXTB0, NXTB1, S) do {  \
    STAGE(p2, (S) + 2);                                                        \
    __builtin_amdgcn_sched_barrier(0);                                         \
    asm volatile("s_waitcnt vmcnt(6)" ::: "memory");                           \
    __builtin_amdgcn_sched_barrier(0);                                         \
    __builtin_amdgcn_s_barrier();                                              \
    LOADFRAGS(p1, NXTA0, NXTA1, NXTB0, NXTB1);                                 \
    PIN(NXTA0); PIN(NXTA1); PIN(NXTB0); PIN(NXTB1);                            \
    __builtin_amdgcn_sched_barrier(0);                                         \
    __builtin_amdgcn_s_setprio(1);                                             \
    MFMA32(CURA0, CURA1, CURB0, CURB1);                                        \
    __builtin_amdgcn_s_setprio(0);                                             \
    asm volatile("s_waitcnt lgkmcnt(0)" ::: "memory");                         \
    __builtin_amdgcn_sched_barrier(0);                                         \
    { char* _t = p0; p0 = p1; p1 = p2; p2 = _t; }                              \
} while (0)

    for (int t = 0; t < 15; ++t) {
        const int s = 2 * t;
        BODY(Ae0, Ae1, Be0, Be1, Ao0, Ao1, Bo0, Bo1, s);
        BODY(Ao0, Ao1, Bo0, Bo1, Ae0, Ae1, Be0, Be1, s + 1);
    }
    asm volatile("s_waitcnt vmcnt(0)" ::: "memory");
    __builtin_amdgcn_sched_barrier(0);
    __builtin_amdgcn_s_barrier();
    LOADFRAGS(p1, Ao0, Ao1, Bo0, Bo1);
    PIN(Ao0); PIN(Ao1); PIN(Bo0); PIN(Bo1);
    __builtin_amdgcn_sched_barrier(0);
    __builtin_amdgcn_s_setprio(1);
    MFMA32(Ae0, Ae1, Be0, Be1);
    __builtin_amdgcn_s_setprio(0);
    asm volatile("s_waitcnt lgkmcnt(0)" ::: "memory");
    __builtin_amdgcn_sched_barrier(0);
    MFMA32(Ao0, Ao1, Bo0, Bo1);

    #pragma unroll
    for (int j = 0; j < 4; ++j) {
        int col = tileN + wn * 64 + j * 16 + (l & 15);
        float bj = bias[col];
        #pragma unroll
        for (int i = 0; i < 4; ++i) {
            int rw = tileM + wm * 64 + i * 16 + (l >> 4) * 4;
            #pragma unroll
            for (int r = 0; r < 4; ++r)
                C[(size_t)(rw + r) * DIM + col] = acc[i][j][r] + bj;
        }
    }
}

extern "C" void kernel_launch(void* const* d_in, const int* in_sizes, int n_in,
                              void* d_out, int out_size, void* d_ws, size_t ws_size,
                              hipStream_t stream) {
    const float* x     = (const float*)d_in[0];
    const int*   rows0 = (const int*)  d_in[1];
    const int*   cols0 = (const int*)  d_in[2];
    const float* vals0 = (const float*)d_in[3];
    const int*   rows1 = (const int*)  d_in[4];
    const int*   cols1 = (const int*)  d_in[5];
    const float* vals1 = (const float*)d_in[6];
    const int*   rows2 = (const int*)  d_in[7];
    const int*   cols2 = (const int*)  d_in[8];
    const float* vals2 = (const float*)d_in[9];
    const float* bias  = (const float*)d_in[10];
    float* out = (float*)d_out;

    char* ws = (char*)d_ws;
    unsigned short* Mc = (unsigned short*)ws;                 // 8 MB
    unsigned short* Xb = (unsigned short*)(ws + 8388608);     // 16 MB
    int*   offb = (int*)(ws + 25165824);      // 3 * 2052
    int*   curb = offb + 3 * 2052;            // 3 * 2048
    int*   colb = curb + 3 * DIM;             // 3 * 16384
    float* valb = (float*)(colb + 3 * NNZc);  // 3 * 16384

    void* prepArgs[] = {(void*)&x, (void*)&Xb,
                        (void*)&rows0, (void*)&cols0, (void*)&vals0,
                        (void*)&rows1, (void*)&cols1, (void*)&vals1,
                        (void*)&rows2, (void*)&cols2, (void*)&vals2,
                        (void*)&curb, (void*)&offb, (void*)&colb, (void*)&valb,
                        (void*)&Mc};
    hipLaunchCooperativeKernel((const void*)prep_kernel, dim3(PREP_BLOCKS), dim3(NT),
                               prepArgs, 0, stream);

    (void)hipFuncSetAttribute((const void*)gemm8,
                              hipFuncAttributeMaxDynamicSharedMemorySize, GEMM_LDS);
    gemm8<<<256, 512, GEMM_LDS, stream>>>(Xb, Mc, bias, out);
}

// Round 16
// 75.626 us; speedup vs baseline: 6.4655x; 6.4655x over previous
//
#include <hip/hip_runtime.h>

// SparseProductLayer:  out = x @ (M0*M1*M2)^T + bias
// Pipeline: zero -> hist -> scan -> scatter -> [mcbuild+xconv fused] ->
// MFMA GEMM (r14 core: BM=128,BN=256,BK=64, 3-slot ring, vmcnt(6), pinned
// frag dbuf, chunk^row&7 swizzle, setprio, XCD-chunked block swizzle).

#define BATCH 4096
#define DIM   2048
#define NNZc  16384
#define NT    256

typedef short bf16x8 __attribute__((ext_vector_type(8)));
typedef float f32x4  __attribute__((ext_vector_type(4)));

__device__ __forceinline__ unsigned short f2bf(float f) {
    unsigned u = __float_as_uint(f);
    unsigned r = (u + 0x7fffu + ((u >> 16) & 1u)) >> 16;   // RNE
    return (unsigned short)r;
}

__device__ __forceinline__ void gload16(const void* g, void* l) {
    __builtin_amdgcn_global_load_lds((const __attribute__((address_space(1))) void*)g,
                                     (__attribute__((address_space(3))) void*)l, 16, 0, 0);
}

// ---- zero the 3*2048 counters ----
__global__ void zero_kernel(int* __restrict__ p) {
    int i = blockIdx.x * NT + threadIdx.x;
    if (i < 3 * DIM) p[i] = 0;
}

// ---- CSR build: histogram (192 blocks) ----
__global__ void hist_kernel(const int* __restrict__ rows0, const int* __restrict__ rows1,
                            const int* __restrict__ rows2, int* __restrict__ cur) {
    int e = blockIdx.x * NT + threadIdx.x;          // 0 .. 3*NNZ
    int m = e >> 14, i = e & (NNZc - 1);
    const int* rp = (m == 0) ? rows0 : (m == 1) ? rows1 : rows2;
    atomicAdd(&cur[m * DIM + rp[i]], 1);
}

// ---- CSR build: exclusive scan of 2048 counts (parallel shuffle scan) ----
__global__ void scan_kernel(int* __restrict__ curb, int* __restrict__ offb) {
    int* cur = curb + blockIdx.x * DIM;
    int* off = offb + blockIdx.x * 2052;
    __shared__ int wsum[4];
    int t = threadIdx.x;
    int c[8]; int s = 0;
    #pragma unroll
    for (int i = 0; i < 8; ++i) { c[i] = cur[t * 8 + i]; s += c[i]; }
    int l = t & 63, wv = t >> 6;
    int v = s;
    #pragma unroll
    for (int d = 1; d < 64; d <<= 1) {
        int u = __shfl_up(v, d, 64);
        if (l >= d) v += u;
    }
    if (l == 63) wsum[wv] = v;
    __syncthreads();
    int wbase = 0;
    for (int i = 0; i < wv; ++i) wbase += wsum[i];
    int base = wbase + v - s;
    #pragma unroll
    for (int i = 0; i < 8; ++i) {
        int idx = t * 8 + i;
        off[idx] = base; cur[idx] = base; base += c[i];
    }
    if (t == 0) off[DIM] = NNZc;
}

// ---- CSR build: scatter entries into row buckets ----
__global__ void scatter_kernel(const int* __restrict__ rows0, const int* __restrict__ cols0,
                               const float* __restrict__ vals0,
                               const int* __restrict__ rows1, const int* __restrict__ cols1,
                               const float* __restrict__ vals1,
                               const int* __restrict__ rows2, const int* __restrict__ cols2,
                               const float* __restrict__ vals2,
                               int* __restrict__ cur,
                               int* __restrict__ colb, float* __restrict__ valb) {
    int e = blockIdx.x * NT + threadIdx.x;
    int m = e >> 14, i = e & (NNZc - 1);
    const int*   rp = (m == 0) ? rows0 : (m == 1) ? rows1 : rows2;
    const int*   cp = (m == 0) ? cols0 : (m == 1) ? cols1 : cols2;
    const float* vp = (m == 0) ? vals0 : (m == 1) ? vals1 : vals2;
    int slot = atomicAdd(&cur[m * DIM + rp[i]], 1);
    colb[m * NNZc + slot] = cp[i];
    valb[m * NNZc + slot] = vp[i];
}

// ---- fused mcbuild + xconv: 1024 blocks. xconv part streams x->bf16 (memory
// pipe); mcbuild part is latency-bound pointer-chasing (LDS) -- they overlap.
#define RPB  2
#define PCAP 2048
__global__ __launch_bounds__(NT) void mcxconv_kernel(
        const float* __restrict__ x, unsigned short* __restrict__ Xb,
        const int* __restrict__ offb, const int* __restrict__ colb,
        const float* __restrict__ valb, unsigned short* __restrict__ Mc) {
    // ---- xconv: this block's 4 chunks of 2048 elements ----
    #pragma unroll
    for (int u = 0; u < 4; ++u) {
        size_t i = (((size_t)blockIdx.x * 4 + u) * NT + threadIdx.x) * 8;
        float4 a = *(const float4*)(x + i);
        float4 b = *(const float4*)(x + i + 4);
        unsigned short o[8] = {f2bf(a.x), f2bf(a.y), f2bf(a.z), f2bf(a.w),
                               f2bf(b.x), f2bf(b.y), f2bf(b.z), f2bf(b.w)};
        *(ulonglong2*)(Xb + i) = *(ulonglong2*)o;
    }

    // ---- mcbuild: rows 2b, 2b+1 via 3-level tree walk in LDS ----
    const int* off0 = offb;              const int* off1 = offb + 2052;  const int* off2 = offb + 4104;
    const int* col0 = colb;              const int* col1 = colb + NNZc;  const int* col2 = colb + 2 * NNZc;
    const float* val0 = valb;            const float* val1 = valb + NNZc; const float* val2 = valb + 2 * NNZc;

    __shared__ float acc[RPB * DIM];
    __shared__ int   pk[PCAP];
    __shared__ float pw[PCAP];
    __shared__ int   npairs;

    const int tid = threadIdx.x;
    const int r0  = blockIdx.x * RPB;

    f32x4* az = (f32x4*)acc;
    #pragma unroll
    for (int j = tid; j < RPB * DIM / 4; j += NT) az[j] = (f32x4){0.f, 0.f, 0.f, 0.f};
    if (tid == 0) npairs = 0;
    __syncthreads();

    #pragma unroll
    for (int k = 0; k < RPB; ++k) {
        int b = off0[r0 + k], e = off0[r0 + k + 1];
        for (int i = b + tid; i < e; i += NT) {
            int   c0 = col0[i];
            float v0 = val0[i];
            int b1 = off1[c0], e1 = off1[c0 + 1];
            for (int j = b1; j < e1; ++j) {
                float w = v0 * val1[j];
                int   c1 = col1[j];
                int slot = atomicAdd(&npairs, 1);
                if (slot < PCAP) { pk[slot] = (k << 16) | c1; pw[slot] = w; }
                else {
                    int b2 = off2[c1], e2 = off2[c1 + 1];
                    for (int q = b2; q < e2; ++q)
                        atomicAdd(&acc[k * DIM + col2[q]], w * val2[q]);
                }
            }
        }
    }
    __syncthreads();

    int np = min(npairs, PCAP);
    for (int p = tid; p < np; p += NT) {
        int   k  = pk[p] >> 16, c1 = pk[p] & 0xffff;
        float w  = pw[p];
        int b2 = off2[c1], e2 = off2[c1 + 1];
        for (int q = b2; q < e2; ++q)
            atomicAdd(&acc[k * DIM + col2[q]], w * val2[q]);
    }
    __syncthreads();

    #pragma unroll
    for (int k = 0; k < RPB; ++k) {
        unsigned short o[8];
        #pragma unroll
        for (int jj = 0; jj < 8; ++jj) o[jj] = f2bf(acc[k * DIM + tid * 8 + jj]);
        *(ulonglong2*)(Mc + (size_t)(r0 + k) * DIM + tid * 8) = *(ulonglong2*)o;
    }
}

// ---- GEMM: C = Xb(4096x2048) @ Mc^T + bias (r14 core, byte-identical) ----
#define BM 128
#define BN 256
#define BK 64
#define NS (DIM / BK)                   // 32
#define A_SL (BM * BK * 2)              // 16384
#define B_SL (BN * BK * 2)              // 32768
#define SLOT (A_SL + B_SL)              // 49152
#define GEMM_LDS (3 * SLOT)             // 147456

__global__ __launch_bounds__(512, 2) void gemm8(
        const unsigned short* __restrict__ A,   // Xb [4096][2048]
        const unsigned short* __restrict__ Bm,  // Mc [2048][2048]
        const float* __restrict__ bias,
        float* __restrict__ C) {
    extern __shared__ char smem[];
    const int tid = threadIdx.x;
    const int l = tid & 63, w = tid >> 6;
    const int wm = w & 1, wn = w >> 1;          // 2M x 4N wave grid, tile 64x64

    // XCD-chunked swizzle: xcd k=(bid&7) owns an 8y x 4x region
    const int bid = blockIdx.x;
    const int k = bid & 7, c = bid >> 3;
    const int tileM = ((k >> 1) * 8 + (c >> 2)) * BM;
    const int tileN = ((k & 1) * 4 + (c & 3)) * BN;

    const int r8   = l >> 3;
    const int clog = (l & 7) ^ r8;
    const unsigned short* aS0 = A  + (size_t)(tileM + 8 * w + r8) * DIM + clog * 8;
    const unsigned short* aS1 = aS0 + (size_t)64 * DIM;
    const unsigned short* bS0 = Bm + (size_t)(tileN + 32 * w + r8) * DIM + clog * 8;

#define STAGE(z, s) do {                                                   \
    gload16(aS0 +                (size_t)(s) * BK, (z) + w * 1024);        \
    gload16(aS1 +                (size_t)(s) * BK, (z) + 8192 + w * 1024); \
    gload16(bS0 +                (size_t)(s) * BK, (z) + A_SL + w * 4096);        \
    gload16(bS0 +  8 * DIM +     (size_t)(s) * BK, (z) + A_SL + w * 4096 + 1024); \
    gload16(bS0 + 16 * DIM +     (size_t)(s) * BK, (z) + A_SL + w * 4096 + 2048); \
    gload16(bS0 + 24 * DIM +     (size_t)(s) * BK, (z) + A_SL + w * 4096 + 3072); \
} while (0)

    const int rbyte = (l & 15) * 128;
    const int c0 = (((l >> 4)    ) ^ (l & 7)) * 16;   // ks=0
    const int c1 = (((l >> 4) + 4) ^ (l & 7)) * 16;   // ks=1

#define LOADFRAGS(z, A0, A1, B0, B1) do {                            \
    const char* _ab = (z) + wm * 8192 + rbyte;                       \
    A0[0] = *(const bf16x8*)(_ab + 0 * 2048 + c0);                   \
    A1[0] = *(const bf16x8*)(_ab + 0 * 2048 + c1);                   \
    A0[1] = *(const bf16x8*)(_ab + 1 * 2048 + c0);                   \
    A1[1] = *(const bf16x8*)(_ab + 1 * 2048 + c1);                   \
    A0[2] = *(const bf16x8*)(_ab + 2 * 2048 + c0);                   \
    A1[2] = *(const bf16x8*)(_ab + 2 * 2048 + c1);                   \
    A0[3] = *(const bf16x8*)(_ab + 3 * 2048 + c0);                   \
    A1[3] = *(const bf16x8*)(_ab + 3 * 2048 + c1);                   \
    const char* _bb = (z) + A_SL + wn * 8192 + rbyte;                \
    B0[0] = *(const bf16x8*)(_bb + 0 * 2048 + c0);                   \
    B1[0] = *(const bf16x8*)(_bb + 0 * 2048 + c1);                   \
    B0[1] = *(const bf16x8*)(_bb + 1 * 2048 + c0);                   \
    B1[1] = *(const bf16x8*)(_bb + 1 * 2048 + c1);                   \
    B0[2] = *(const bf16x8*)(_bb + 2 * 2048 + c0);                   \
    B1[2] = *(const bf16x8*)(_bb + 2 * 2048 + c1);                   \
    B0[3] = *(const bf16x8*)(_bb + 3 * 2048 + c0);                   \
    B1[3] = *(const bf16x8*)(_bb + 3 * 2048 + c1);                   \
} while (0)

#define PIN(X) asm volatile("" : "+v"(X[0]), "+v"(X[1]), "+v"(X[2]), "+v"(X[3]))

#define MFMA32(A0, A1, B0, B1) do {                                                    \
    _Pragma("unroll")                                                                  \
    for (int _q = 0; _q < 4; ++_q)                                                     \
        _Pragma("unroll")                                                              \
        for (int _j = 0; _j < 4; ++_j) {                                               \
            acc[_q][_j] = __builtin_amdgcn_mfma_f32_16x16x32_bf16(A0[_q], B0[_j],      \
                                                                  acc[_q][_j], 0,0,0); \
            acc[_q][_j] = __builtin_amdgcn_mfma_f32_16x16x32_bf16(A1[_q], B1[_j],      \
                                                                  acc[_q][_j], 0,0,0); \
        }                                                                              \
} while (0)

    bf16x8 Ae0[4], Ae1[4], Be0[4], Be1[4];
    bf16x8 Ao0[4], Ao1[4], Bo0[4], Bo1[4];
    f32x4 acc[4][4] = {};

    char* p0 = smem;
    char* p1 = smem + SLOT;
    char* p2 = smem + 2 * SLOT;

    STAGE(p0, 0);
    STAGE(p1, 1);
    asm volatile("s_waitcnt vmcnt(6)" ::: "memory");
    __builtin_amdgcn_sched_barrier(0);
    __builtin_amdgcn_s_barrier();
    LOADFRAGS(p0, Ae0, Ae1, Be0, Be1);
    PIN(Ae0); PIN(Ae1); PIN(Be0); PIN(Be1);
    asm volatile("s_waitcnt lgkmcnt(0)" ::: "memory");
    __builtin_amdgcn_sched_barrier(0);

#define BODY(CURA0, CURA1, CURB0, CURB1, NXTA0, NXTA1, NXTB0, NXTB1, S) do {  \
    STAGE(p2, (S) + 2);                                                        \
    __builtin_amdgcn_sched_barrier(0);                                         \
    asm volatile("s_waitcnt vmcnt(6)" ::: "memory");                           \
    __builtin_amdgcn_sched_barrier(0);                                         \
    __builtin_amdgcn_s_barrier();                                              \
    LOADFRAGS(p1, NXTA0, NXTA1, NXTB0, NXTB1);                                 \
    PIN(NXTA0); PIN(NXTA1); PIN(NXTB0); PIN(NXTB1);                            \
    __builtin_amdgcn_sched_barrier(0);                                         \
    __builtin_amdgcn_s_setprio(1);                                             \
    MFMA32(CURA0, CURA1, CURB0, CURB1);                                        \
    __builtin_amdgcn_s_setprio(0);                                             \
    asm volatile("s_waitcnt lgkmcnt(0)" ::: "memory");                         \
    __builtin_amdgcn_sched_barrier(0);                                         \
    { char* _t = p0; p0 = p1; p1 = p2; p2 = _t; }                              \
} while (0)

    for (int t = 0; t < 15; ++t) {
        const int s = 2 * t;
        BODY(Ae0, Ae1, Be0, Be1, Ao0, Ao1, Bo0, Bo1, s);
        BODY(Ao0, Ao1, Bo0, Bo1, Ae0, Ae1, Be0, Be1, s + 1);
    }
    asm volatile("s_waitcnt vmcnt(0)" ::: "memory");
    __builtin_amdgcn_sched_barrier(0);
    __builtin_amdgcn_s_barrier();
    LOADFRAGS(p1, Ao0, Ao1, Bo0, Bo1);
    PIN(Ao0); PIN(Ao1); PIN(Bo0); PIN(Bo1);
    __builtin_amdgcn_sched_barrier(0);
    __builtin_amdgcn_s_setprio(1);
    MFMA32(Ae0, Ae1, Be0, Be1);
    __builtin_amdgcn_s_setprio(0);
    asm volatile("s_waitcnt lgkmcnt(0)" ::: "memory");
    __builtin_amdgcn_sched_barrier(0);
    MFMA32(Ao0, Ao1, Bo0, Bo1);

    #pragma unroll
    for (int j = 0; j < 4; ++j) {
        int col = tileN + wn * 64 + j * 16 + (l & 15);
        float bj = bias[col];
        #pragma unroll
        for (int i = 0; i < 4; ++i) {
            int rw = tileM + wm * 64 + i * 16 + (l >> 4) * 4;
            #pragma unroll
            for (int r = 0; r < 4; ++r)
                C[(size_t)(rw + r) * DIM + col] = acc[i][j][r] + bj;
        }
    }
}

extern "C" void kernel_launch(void* const* d_in, const int* in_sizes, int n_in,
                              void* d_out, int out_size, void* d_ws, size_t ws_size,
                              hipStream_t stream) {
    const float* x     = (const float*)d_in[0];
    const int*   rows0 = (const int*)  d_in[1];
    const int*   cols0 = (const int*)  d_in[2];
    const float* vals0 = (const float*)d_in[3];
    const int*   rows1 = (const int*)  d_in[4];
    const int*   cols1 = (const int*)  d_in[5];
    const float* vals1 = (const float*)d_in[6];
    const int*   rows2 = (const int*)  d_in[7];
    const int*   cols2 = (const int*)  d_in[8];
    const float* vals2 = (const float*)d_in[9];
    const float* bias  = (const float*)d_in[10];
    float* out = (float*)d_out;

    char* ws = (char*)d_ws;
    unsigned short* Mc = (unsigned short*)ws;                 // 8 MB
    unsigned short* Xb = (unsigned short*)(ws + 8388608);     // 16 MB
    int*   offb = (int*)(ws + 25165824);      // 3 * 2052
    int*   curb = offb + 3 * 2052;            // 3 * 2048
    int*   colb = curb + 3 * DIM;             // 3 * 16384
    float* valb = (float*)(colb + 3 * NNZc);  // 3 * 16384

    zero_kernel<<<(3 * DIM + NT - 1) / NT, NT, 0, stream>>>(curb);
    hist_kernel<<<3 * NNZc / NT, NT, 0, stream>>>(rows0, rows1, rows2, curb);
    scan_kernel<<<3, NT, 0, stream>>>(curb, offb);
    scatter_kernel<<<3 * NNZc / NT, NT, 0, stream>>>(rows0, cols0, vals0,
                                                     rows1, cols1, vals1,
                                                     rows2, cols2, vals2,
                                                     curb, colb, valb);
    mcxconv_kernel<<<DIM / RPB, NT, 0, stream>>>(x, Xb, offb, colb, valb, Mc);

    (void)hipFuncSetAttribute((const void*)gemm8,
                              hipFuncAttributeMaxDynamicSharedMemorySize, GEMM_LDS);
    gemm8<<<256, 512, GEMM_LDS, stream>>>(Xb, Mc, bias, out);
}

// Round 17
// 70.030 us; speedup vs baseline: 6.9821x; 1.0799x over previous
//
#include <hip/hip_runtime.h>

// SparseProductLayer:  out = x @ (M0*M1*M2)^T + bias
// Pipeline (4 launches): zero counters -> direct padded-bucket scatter ->
// [mcbuild+xconv fused] -> MFMA GEMM (r14 core: BM=128,BN=256,BK=64, 3-slot
// ring, vmcnt(6), pinned frag dbuf, chunk^row&7 swizzle, setprio, XCD-chunked
// block swizzle).

#define BATCH 4096
#define DIM   2048
#define NNZc  16384
#define NT    256
#define BCAP  40      // bucket capacity per row (Poisson lambda=8 -> P(>40)~0)

typedef short bf16x8 __attribute__((ext_vector_type(8)));
typedef float f32x4  __attribute__((ext_vector_type(4)));

__device__ __forceinline__ unsigned short f2bf(float f) {
    unsigned u = __float_as_uint(f);
    unsigned r = (u + 0x7fffu + ((u >> 16) & 1u)) >> 16;   // RNE
    return (unsigned short)r;
}

__device__ __forceinline__ void gload16(const void* g, void* l) {
    __builtin_amdgcn_global_load_lds((const __attribute__((address_space(1))) void*)g,
                                     (__attribute__((address_space(3))) void*)l, 16, 0, 0);
}

// ---- zero the 3*2048 counters ----
__global__ void zero_kernel(int* __restrict__ p) {
    int i = blockIdx.x * NT + threadIdx.x;
    if (i < 3 * DIM) p[i] = 0;
}

// ---- direct scatter into padded row buckets (replaces hist+scan+scatter) ----
__global__ void scatterd_kernel(const int* __restrict__ rows0, const int* __restrict__ cols0,
                                const float* __restrict__ vals0,
                                const int* __restrict__ rows1, const int* __restrict__ cols1,
                                const float* __restrict__ vals1,
                                const int* __restrict__ rows2, const int* __restrict__ cols2,
                                const float* __restrict__ vals2,
                                int* __restrict__ cnt,
                                int* __restrict__ colB, float* __restrict__ valB) {
    int e = blockIdx.x * NT + threadIdx.x;          // 0 .. 3*NNZ
    int m = e >> 14, i = e & (NNZc - 1);
    const int*   rp = (m == 0) ? rows0 : (m == 1) ? rows1 : rows2;
    const int*   cp = (m == 0) ? cols0 : (m == 1) ? cols1 : cols2;
    const float* vp = (m == 0) ? vals0 : (m == 1) ? vals1 : vals2;
    int r = rp[i];
    int slot = atomicAdd(&cnt[m * DIM + r], 1);
    if (slot < BCAP) {
        colB[(m * DIM + r) * BCAP + slot] = cp[i];
        valB[(m * DIM + r) * BCAP + slot] = vp[i];
    }
}

// ---- fused mcbuild + xconv: 1024 blocks ----
#define RPB  2
#define PCAP 2048
__global__ __launch_bounds__(NT) void mcxconv_kernel(
        const float* __restrict__ x, unsigned short* __restrict__ Xb,
        const int* __restrict__ cnt, const int* __restrict__ colB,
        const float* __restrict__ valB, unsigned short* __restrict__ Mc) {
    // ---- xconv: this block's 4 chunks of 2048 elements ----
    #pragma unroll
    for (int u = 0; u < 4; ++u) {
        size_t i = (((size_t)blockIdx.x * 4 + u) * NT + threadIdx.x) * 8;
        float4 a = *(const float4*)(x + i);
        float4 b = *(const float4*)(x + i + 4);
        unsigned short o[8] = {f2bf(a.x), f2bf(a.y), f2bf(a.z), f2bf(a.w),
                               f2bf(b.x), f2bf(b.y), f2bf(b.z), f2bf(b.w)};
        *(ulonglong2*)(Xb + i) = *(ulonglong2*)o;
    }

    // ---- mcbuild: rows 2b, 2b+1 via 3-level bucket tree walk in LDS ----
    __shared__ float acc[RPB * DIM];
    __shared__ int   pk[PCAP];
    __shared__ float pw[PCAP];
    __shared__ int   npairs;

    const int tid = threadIdx.x;
    const int r0  = blockIdx.x * RPB;

    f32x4* az = (f32x4*)acc;
    #pragma unroll
    for (int j = tid; j < RPB * DIM / 4; j += NT) az[j] = (f32x4){0.f, 0.f, 0.f, 0.f};
    if (tid == 0) npairs = 0;
    __syncthreads();

    #pragma unroll
    for (int k = 0; k < RPB; ++k) {
        int row = r0 + k;
        int n0 = min(cnt[row], BCAP);
        for (int i = tid; i < n0; i += NT) {
            int   c0 = colB[row * BCAP + i];
            float v0 = valB[row * BCAP + i];
            int n1 = min(cnt[DIM + c0], BCAP);
            for (int j = 0; j < n1; ++j) {
                float w  = v0 * valB[(DIM + c0) * BCAP + j];
                int   c1 = colB[(DIM + c0) * BCAP + j];
                int slot = atomicAdd(&npairs, 1);
                if (slot < PCAP) { pk[slot] = (k << 16) | c1; pw[slot] = w; }
                else {
                    int n2 = min(cnt[2 * DIM + c1], BCAP);
                    for (int q = 0; q < n2; ++q)
                        atomicAdd(&acc[k * DIM + colB[(2 * DIM + c1) * BCAP + q]],
                                  w * valB[(2 * DIM + c1) * BCAP + q]);
                }
            }
        }
    }
    __syncthreads();

    int np = min(npairs, PCAP);
    for (int p = tid; p < np; p += NT) {
        int   k  = pk[p] >> 16, c1 = pk[p] & 0xffff;
        float w  = pw[p];
        int n2 = min(cnt[2 * DIM + c1], BCAP);
        const int*   cb = colB + (2 * DIM + c1) * BCAP;
        const float* vb = valB + (2 * DIM + c1) * BCAP;
        for (int q = 0; q < n2; ++q)
            atomicAdd(&acc[k * DIM + cb[q]], w * vb[q]);
    }
    __syncthreads();

    #pragma unroll
    for (int k = 0; k < RPB; ++k) {
        unsigned short o[8];
        #pragma unroll
        for (int jj = 0; jj < 8; ++jj) o[jj] = f2bf(acc[k * DIM + tid * 8 + jj]);
        *(ulonglong2*)(Mc + (size_t)(r0 + k) * DIM + tid * 8) = *(ulonglong2*)o;
    }
}

// ---- GEMM: C = Xb(4096x2048) @ Mc^T + bias (r14 core, byte-identical) ----
#define BM 128
#define BN 256
#define BK 64
#define NS (DIM / BK)                   // 32
#define A_SL (BM * BK * 2)              // 16384
#define B_SL (BN * BK * 2)              // 32768
#define SLOT (A_SL + B_SL)              // 49152
#define GEMM_LDS (3 * SLOT)             // 147456

__global__ __launch_bounds__(512, 2) void gemm8(
        const unsigned short* __restrict__ A,   // Xb [4096][2048]
        const unsigned short* __restrict__ Bm,  // Mc [2048][2048]
        const float* __restrict__ bias,
        float* __restrict__ C) {
    extern __shared__ char smem[];
    const int tid = threadIdx.x;
    const int l = tid & 63, w = tid >> 6;
    const int wm = w & 1, wn = w >> 1;          // 2M x 4N wave grid, tile 64x64

    // XCD-chunked swizzle: xcd k=(bid&7) owns an 8y x 4x region
    const int bid = blockIdx.x;
    const int k = bid & 7, c = bid >> 3;
    const int tileM = ((k >> 1) * 8 + (c >> 2)) * BM;
    const int tileN = ((k & 1) * 4 + (c & 3)) * BN;

    const int r8   = l >> 3;
    const int clog = (l & 7) ^ r8;
    const unsigned short* aS0 = A  + (size_t)(tileM + 8 * w + r8) * DIM + clog * 8;
    const unsigned short* aS1 = aS0 + (size_t)64 * DIM;
    const unsigned short* bS0 = Bm + (size_t)(tileN + 32 * w + r8) * DIM + clog * 8;

#define STAGE(z, s) do {                                                   \
    gload16(aS0 +                (size_t)(s) * BK, (z) + w * 1024);        \
    gload16(aS1 +                (size_t)(s) * BK, (z) + 8192 + w * 1024); \
    gload16(bS0 +                (size_t)(s) * BK, (z) + A_SL + w * 4096);        \
    gload16(bS0 +  8 * DIM +     (size_t)(s) * BK, (z) + A_SL + w * 4096 + 1024); \
    gload16(bS0 + 16 * DIM +     (size_t)(s) * BK, (z) + A_SL + w * 4096 + 2048); \
    gload16(bS0 + 24 * DIM +     (size_t)(s) * BK, (z) + A_SL + w * 4096 + 3072); \
} while (0)

    const int rbyte = (l & 15) * 128;
    const int c0 = (((l >> 4)    ) ^ (l & 7)) * 16;   // ks=0
    const int c1 = (((l >> 4) + 4) ^ (l & 7)) * 16;   // ks=1

#define LOADFRAGS(z, A0, A1, B0, B1) do {                            \
    const char* _ab = (z) + wm * 8192 + rbyte;                       \
    A0[0] = *(const bf16x8*)(_ab + 0 * 2048 + c0);                   \
    A1[0] = *(const bf16x8*)(_ab + 0 * 2048 + c1);                   \
    A0[1] = *(const bf16x8*)(_ab + 1 * 2048 + c0);                   \
    A1[1] = *(const bf16x8*)(_ab + 1 * 2048 + c1);                   \
    A0[2] = *(const bf16x8*)(_ab + 2 * 2048 + c0);                   \
    A1[2] = *(const bf16x8*)(_ab + 2 * 2048 + c1);                   \
    A0[3] = *(const bf16x8*)(_ab + 3 * 2048 + c0);                   \
    A1[3] = *(const bf16x8*)(_ab + 3 * 2048 + c1);                   \
    const char* _bb = (z) + A_SL + wn * 8192 + rbyte;                \
    B0[0] = *(const bf16x8*)(_bb + 0 * 2048 + c0);                   \
    B1[0] = *(const bf16x8*)(_bb + 0 * 2048 + c1);                   \
    B0[1] = *(const bf16x8*)(_bb + 1 * 2048 + c0);                   \
    B1[1] = *(const bf16x8*)(_bb + 1 * 2048 + c1);                   \
    B0[2] = *(const bf16x8*)(_bb + 2 * 2048 + c0);                   \
    B1[2] = *(const bf16x8*)(_bb + 2 * 2048 + c1);                   \
    B0[3] = *(const bf16x8*)(_bb + 3 * 2048 + c0);                   \
    B1[3] = *(const bf16x8*)(_bb + 3 * 2048 + c1);                   \
} while (0)

#define PIN(X) asm volatile("" : "+v"(X[0]), "+v"(X[1]), "+v"(X[2]), "+v"(X[3]))

#define MFMA32(A0, A1, B0, B1) do {                                                    \
    _Pragma("unroll")                                                                  \
    for (int _q = 0; _q < 4; ++_q)                                                     \
        _Pragma("unroll")                                                              \
        for (int _j = 0; _j < 4; ++_j) {                                               \
            acc[_q][_j] = __builtin_amdgcn_mfma_f32_16x16x32_bf16(A0[_q], B0[_j],      \
                                                                  acc[_q][_j], 0,0,0); \
            acc[_q][_j] = __builtin_amdgcn_mfma_f32_16x16x32_bf16(A1[_q], B1[_j],      \
                                                                  acc[_q][_j], 0,0,0); \
        }                                                                              \
} while (0)

    bf16x8 Ae0[4], Ae1[4], Be0[4], Be1[4];
    bf16x8 Ao0[4], Ao1[4], Bo0[4], Bo1[4];
    f32x4 acc[4][4] = {};

    char* p0 = smem;
    char* p1 = smem + SLOT;
    char* p2 = smem + 2 * SLOT;

    STAGE(p0, 0);
    STAGE(p1, 1);
    asm volatile("s_waitcnt vmcnt(6)" ::: "memory");
    __builtin_amdgcn_sched_barrier(0);
    __builtin_amdgcn_s_barrier();
    LOADFRAGS(p0, Ae0, Ae1, Be0, Be1);
    PIN(Ae0); PIN(Ae1); PIN(Be0); PIN(Be1);
    asm volatile("s_waitcnt lgkmcnt(0)" ::: "memory");
    __builtin_amdgcn_sched_barrier(0);

#define BODY(CURA0, CURA1, CURB0, CURB1, NXTA0, NXTA1, NXTB0, NXTB1, S) do {  \
    STAGE(p2, (S) + 2);                                                        \
    __builtin_amdgcn_sched_barrier(0);                                         \
    asm volatile("s_waitcnt vmcnt(6)" ::: "memory");                           \
    __builtin_amdgcn_sched_barrier(0);                                         \
    __builtin_amdgcn_s_barrier();                                              \
    LOADFRAGS(p1, NXTA0, NXTA1, NXTB0, NXTB1);                                 \
    PIN(NXTA0); PIN(NXTA1); PIN(NXTB0); PIN(NXTB1);                            \
    __builtin_amdgcn_sched_barrier(0);                                         \
    __builtin_amdgcn_s_setprio(1);                                             \
    MFMA32(CURA0, CURA1, CURB0, CURB1);                                        \
    __builtin_amdgcn_s_setprio(0);                                             \
    asm volatile("s_waitcnt lgkmcnt(0)" ::: "memory");                         \
    __builtin_amdgcn_sched_barrier(0);                                         \
    { char* _t = p0; p0 = p1; p1 = p2; p2 = _t; }                              \
} while (0)

    for (int t = 0; t < 15; ++t) {
        const int s = 2 * t;
        BODY(Ae0, Ae1, Be0, Be1, Ao0, Ao1, Bo0, Bo1, s);
        BODY(Ao0, Ao1, Bo0, Bo1, Ae0, Ae1, Be0, Be1, s + 1);
    }
    asm volatile("s_waitcnt vmcnt(0)" ::: "memory");
    __builtin_amdgcn_sched_barrier(0);
    __builtin_amdgcn_s_barrier();
    LOADFRAGS(p1, Ao0, Ao1, Bo0, Bo1);
    PIN(Ao0); PIN(Ao1); PIN(Bo0); PIN(Bo1);
    __builtin_amdgcn_sched_barrier(0);
    __builtin_amdgcn_s_setprio(1);
    MFMA32(Ae0, Ae1, Be0, Be1);
    __builtin_amdgcn_s_setprio(0);
    asm volatile("s_waitcnt lgkmcnt(0)" ::: "memory");
    __builtin_amdgcn_sched_barrier(0);
    MFMA32(Ao0, Ao1, Bo0, Bo1);

    #pragma unroll
    for (int j = 0; j < 4; ++j) {
        int col = tileN + wn * 64 + j * 16 + (l & 15);
        float bj = bias[col];
        #pragma unroll
        for (int i = 0; i < 4; ++i) {
            int rw = tileM + wm * 64 + i * 16 + (l >> 4) * 4;
            #pragma unroll
            for (int r = 0; r < 4; ++r)
                C[(size_t)(rw + r) * DIM + col] = acc[i][j][r] + bj;
        }
    }
}

extern "C" void kernel_launch(void* const* d_in, const int* in_sizes, int n_in,
                              void* d_out, int out_size, void* d_ws, size_t ws_size,
                              hipStream_t stream) {
    const float* x     = (const float*)d_in[0];
    const int*   rows0 = (const int*)  d_in[1];
    const int*   cols0 = (const int*)  d_in[2];
    const float* vals0 = (const float*)d_in[3];
    const int*   rows1 = (const int*)  d_in[4];
    const int*   cols1 = (const int*)  d_in[5];
    const float* vals1 = (const float*)d_in[6];
    const int*   rows2 = (const int*)  d_in[7];
    const int*   cols2 = (const int*)  d_in[8];
    const float* vals2 = (const float*)d_in[9];
    const float* bias  = (const float*)d_in[10];
    float* out = (float*)d_out;

    char* ws = (char*)d_ws;
    unsigned short* Mc = (unsigned short*)ws;                 // 8 MB
    unsigned short* Xb = (unsigned short*)(ws + 8388608);     // 16 MB
    int*   cnt  = (int*)(ws + 25165824);           // 3*2048
    int*   colB = cnt + 3 * DIM;                   // 3*2048*BCAP
    float* valB = (float*)(colB + 3 * DIM * BCAP); // 3*2048*BCAP

    zero_kernel<<<(3 * DIM + NT - 1) / NT, NT, 0, stream>>>(cnt);
    scatterd_kernel<<<3 * NNZc / NT, NT, 0, stream>>>(rows0, cols0, vals0,
                                                      rows1, cols1, vals1,
                                                      rows2, cols2, vals2,
                                                      cnt, colB, valB);
    mcxconv_kernel<<<DIM / RPB, NT, 0, stream>>>(x, Xb, cnt, colB, valB, Mc);

    (void)hipFuncSetAttribute((const void*)gemm8,
                              hipFuncAttributeMaxDynamicSharedMemorySize, GEMM_LDS);
    gemm8<<<256, 512, GEMM_LDS, stream>>>(Xb, Mc, bias, out);
}

// Round 18
// 64.705 us; speedup vs baseline: 7.5567x; 1.0823x over previous
//
#include <hip/hip_runtime.h>

// SparseProductLayer:  out = x @ (M0*M1*M2)^T + bias
// Pipeline (4 launches): zero counters -> direct padded-bucket scatter (int2)
// -> [mcbuild+xconv fused, 2-D parallel expansion] -> MFMA GEMM (r14 core:
// BM=128,BN=256,BK=64, 3-slot ring, vmcnt(6), pinned frag dbuf, chunk^row&7
// swizzle, setprio, XCD-chunked block swizzle).

#define BATCH 4096
#define DIM   2048
#define NNZc  16384
#define NT    256
#define BCAP  40      // bucket capacity per row (Poisson lambda=8 -> P(>40)~0)

typedef short bf16x8 __attribute__((ext_vector_type(8)));
typedef float f32x4  __attribute__((ext_vector_type(4)));

__device__ __forceinline__ unsigned short f2bf(float f) {
    unsigned u = __float_as_uint(f);
    unsigned r = (u + 0x7fffu + ((u >> 16) & 1u)) >> 16;   // RNE
    return (unsigned short)r;
}

__device__ __forceinline__ void gload16(const void* g, void* l) {
    __builtin_amdgcn_global_load_lds((const __attribute__((address_space(1))) void*)g,
                                     (__attribute__((address_space(3))) void*)l, 16, 0, 0);
}

// ---- zero the 3*2048 counters ----
__global__ void zero_kernel(int* __restrict__ p) {
    int i = blockIdx.x * NT + threadIdx.x;
    if (i < 3 * DIM) p[i] = 0;
}

// ---- direct scatter into padded row buckets, (col,val) packed as int2 ----
__global__ void scatterd_kernel(const int* __restrict__ rows0, const int* __restrict__ cols0,
                                const float* __restrict__ vals0,
                                const int* __restrict__ rows1, const int* __restrict__ cols1,
                                const float* __restrict__ vals1,
                                const int* __restrict__ rows2, const int* __restrict__ cols2,
                                const float* __restrict__ vals2,
                                int* __restrict__ cnt, int2* __restrict__ bkt) {
    int e = blockIdx.x * NT + threadIdx.x;          // 0 .. 3*NNZ
    int m = e >> 14, i = e & (NNZc - 1);
    const int*   rp = (m == 0) ? rows0 : (m == 1) ? rows1 : rows2;
    const int*   cp = (m == 0) ? cols0 : (m == 1) ? cols1 : cols2;
    const float* vp = (m == 0) ? vals0 : (m == 1) ? vals1 : vals2;
    int r = rp[i];
    int slot = atomicAdd(&cnt[m * DIM + r], 1);
    if (slot < BCAP)
        bkt[(m * DIM + r) * BCAP + slot] = make_int2(cp[i], __float_as_int(vp[i]));
}

// ---- fused mcbuild + xconv: 1024 blocks, 2-D parallel tree expansion ----
#define RPB  2
#define PCAP 2048
__global__ __launch_bounds__(NT) void mcxconv_kernel(
        const float* __restrict__ x, unsigned short* __restrict__ Xb,
        const int* __restrict__ cnt, const int2* __restrict__ bkt,
        unsigned short* __restrict__ Mc) {
    // ---- xconv: this block's 4 chunks of 2048 elements ----
    #pragma unroll
    for (int u = 0; u < 4; ++u) {
        size_t i = (((size_t)blockIdx.x * 4 + u) * NT + threadIdx.x) * 8;
        float4 a = *(const float4*)(x + i);
        float4 b = *(const float4*)(x + i + 4);
        unsigned short o[8] = {f2bf(a.x), f2bf(a.y), f2bf(a.z), f2bf(a.w),
                               f2bf(b.x), f2bf(b.y), f2bf(b.z), f2bf(b.w)};
        *(ulonglong2*)(Xb + i) = *(ulonglong2*)o;
    }

    // ---- mcbuild: rows 2b, 2b+1 via 3-level bucket tree walk in LDS ----
    __shared__ float acc[RPB * DIM];
    __shared__ int   pk[PCAP];
    __shared__ float pw[PCAP];
    __shared__ int   sc0[BCAP];
    __shared__ float sv0[BCAP];
    __shared__ int   npairs;

    const int tid = threadIdx.x;
    const int r0  = blockIdx.x * RPB;

    f32x4* az = (f32x4*)acc;
    #pragma unroll
    for (int j = tid; j < RPB * DIM / 4; j += NT) az[j] = (f32x4){0.f, 0.f, 0.f, 0.f};
    if (tid == 0) npairs = 0;
    __syncthreads();

    // expansion: thread (i0 = tid>>4, jj = tid&15) covers 16 x 16 (i,j) pairs
    const int i0 = tid >> 4, jj = tid & 15;
    #pragma unroll
    for (int k = 0; k < RPB; ++k) {
        int row = r0 + k;
        int n0 = min(cnt[row], BCAP);
        if (tid < n0) {
            int2 e0 = bkt[row * BCAP + tid];
            sc0[tid] = e0.x; sv0[tid] = __int_as_float(e0.y);
        }
        __syncthreads();
        for (int ib = 0; ib < n0; ib += 16) {
            int i = ib + i0;
            if (i < n0) {
                int   c0v = sc0[i];
                float v0  = sv0[i];
                int n1 = min(cnt[DIM + c0v], BCAP);
                for (int j = jj; j < n1; j += 16) {
                    int2  e1 = bkt[(DIM + c0v) * BCAP + j];
                    float w  = v0 * __int_as_float(e1.y);
                    int slot = atomicAdd(&npairs, 1);
                    if (slot < PCAP) { pk[slot] = (k << 16) | e1.x; pw[slot] = w; }
                    else {  // overflow fallback (statistically never)
                        int n2 = min(cnt[2 * DIM + e1.x], BCAP);
                        const int2* b2 = bkt + (2 * DIM + e1.x) * BCAP;
                        for (int q = 0; q < n2; ++q) {
                            int2 e2 = b2[q];
                            atomicAdd(&acc[k * DIM + e2.x], w * __int_as_float(e2.y));
                        }
                    }
                }
            }
        }
        __syncthreads();    // sc0/sv0 reused next k
    }

    int np = min(npairs, PCAP);
    for (int p = tid; p < np; p += NT) {
        int   k  = pk[p] >> 16, c1 = pk[p] & 0xffff;
        float w  = pw[p];
        int n2 = min(cnt[2 * DIM + c1], BCAP);
        const int2* b2 = bkt + (2 * DIM + c1) * BCAP;
        for (int q = 0; q < n2; ++q) {
            int2 e2 = b2[q];
            atomicAdd(&acc[k * DIM + e2.x], w * __int_as_float(e2.y));
        }
    }
    __syncthreads();

    #pragma unroll
    for (int k = 0; k < RPB; ++k) {
        unsigned short o[8];
        #pragma unroll
        for (int jj2 = 0; jj2 < 8; ++jj2) o[jj2] = f2bf(acc[k * DIM + tid * 8 + jj2]);
        *(ulonglong2*)(Mc + (size_t)(r0 + k) * DIM + tid * 8) = *(ulonglong2*)o;
    }
}

// ---- GEMM: C = Xb(4096x2048) @ Mc^T + bias (r14 core, byte-identical) ----
#define BM 128
#define BN 256
#define BK 64
#define NS (DIM / BK)                   // 32
#define A_SL (BM * BK * 2)              // 16384
#define B_SL (BN * BK * 2)              // 32768
#define SLOT (A_SL + B_SL)              // 49152
#define GEMM_LDS (3 * SLOT)             // 147456

__global__ __launch_bounds__(512, 2) void gemm8(
        const unsigned short* __restrict__ A,   // Xb [4096][2048]
        const unsigned short* __restrict__ Bm,  // Mc [2048][2048]
        const float* __restrict__ bias,
        float* __restrict__ C) {
    extern __shared__ char smem[];
    const int tid = threadIdx.x;
    const int l = tid & 63, w = tid >> 6;
    const int wm = w & 1, wn = w >> 1;          // 2M x 4N wave grid, tile 64x64

    // XCD-chunked swizzle: xcd k=(bid&7) owns an 8y x 4x region
    const int bid = blockIdx.x;
    const int k = bid & 7, c = bid >> 3;
    const int tileM = ((k >> 1) * 8 + (c >> 2)) * BM;
    const int tileN = ((k & 1) * 4 + (c & 3)) * BN;

    const int r8   = l >> 3;
    const int clog = (l & 7) ^ r8;
    const unsigned short* aS0 = A  + (size_t)(tileM + 8 * w + r8) * DIM + clog * 8;
    const unsigned short* aS1 = aS0 + (size_t)64 * DIM;
    const unsigned short* bS0 = Bm + (size_t)(tileN + 32 * w + r8) * DIM + clog * 8;

#define STAGE(z, s) do {                                                   \
    gload16(aS0 +                (size_t)(s) * BK, (z) + w * 1024);        \
    gload16(aS1 +                (size_t)(s) * BK, (z) + 8192 + w * 1024); \
    gload16(bS0 +                (size_t)(s) * BK, (z) + A_SL + w * 4096);        \
    gload16(bS0 +  8 * DIM +     (size_t)(s) * BK, (z) + A_SL + w * 4096 + 1024); \
    gload16(bS0 + 16 * DIM +     (size_t)(s) * BK, (z) + A_SL + w * 4096 + 2048); \
    gload16(bS0 + 24 * DIM +     (size_t)(s) * BK, (z) + A_SL + w * 4096 + 3072); \
} while (0)

    const int rbyte = (l & 15) * 128;
    const int c0 = (((l >> 4)    ) ^ (l & 7)) * 16;   // ks=0
    const int c1 = (((l >> 4) + 4) ^ (l & 7)) * 16;   // ks=1

#define LOADFRAGS(z, A0, A1, B0, B1) do {                            \
    const char* _ab = (z) + wm * 8192 + rbyte;                       \
    A0[0] = *(const bf16x8*)(_ab + 0 * 2048 + c0);                   \
    A1[0] = *(const bf16x8*)(_ab + 0 * 2048 + c1);                   \
    A0[1] = *(const bf16x8*)(_ab + 1 * 2048 + c0);                   \
    A1[1] = *(const bf16x8*)(_ab + 1 * 2048 + c1);                   \
    A0[2] = *(const bf16x8*)(_ab + 2 * 2048 + c0);                   \
    A1[2] = *(const bf16x8*)(_ab + 2 * 2048 + c1);                   \
    A0[3] = *(const bf16x8*)(_ab + 3 * 2048 + c0);                   \
    A1[3] = *(const bf16x8*)(_ab + 3 * 2048 + c1);                   \
    const char* _bb = (z) + A_SL + wn * 8192 + rbyte;                \
    B0[0] = *(const bf16x8*)(_bb + 0 * 2048 + c0);                   \
    B1[0] = *(const bf16x8*)(_bb + 0 * 2048 + c1);                   \
    B0[1] = *(const bf16x8*)(_bb + 1 * 2048 + c0);                   \
    B1[1] = *(const bf16x8*)(_bb + 1 * 2048 + c1);                   \
    B0[2] = *(const bf16x8*)(_bb + 2 * 2048 + c0);                   \
    B1[2] = *(const bf16x8*)(_bb + 2 * 2048 + c1);                   \
    B0[3] = *(const bf16x8*)(_bb + 3 * 2048 + c0);                   \
    B1[3] = *(const bf16x8*)(_bb + 3 * 2048 + c1);                   \
} while (0)

#define PIN(X) asm volatile("" : "+v"(X[0]), "+v"(X[1]), "+v"(X[2]), "+v"(X[3]))

#define MFMA32(A0, A1, B0, B1) do {                                                    \
    _Pragma("unroll")                                                                  \
    for (int _q = 0; _q < 4; ++_q)                                                     \
        _Pragma("unroll")                                                              \
        for (int _j = 0; _j < 4; ++_j) {                                               \
            acc[_q][_j] = __builtin_amdgcn_mfma_f32_16x16x32_bf16(A0[_q], B0[_j],      \
                                                                  acc[_q][_j], 0,0,0); \
            acc[_q][_j] = __builtin_amdgcn_mfma_f32_16x16x32_bf16(A1[_q], B1[_j],      \
                                                                  acc[_q][_j], 0,0,0); \
        }                                                                              \
} while (0)

    bf16x8 Ae0[4], Ae1[4], Be0[4], Be1[4];
    bf16x8 Ao0[4], Ao1[4], Bo0[4], Bo1[4];
    f32x4 acc[4][4] = {};

    char* p0 = smem;
    char* p1 = smem + SLOT;
    char* p2 = smem + 2 * SLOT;

    STAGE(p0, 0);
    STAGE(p1, 1);
    asm volatile("s_waitcnt vmcnt(6)" ::: "memory");
    __builtin_amdgcn_sched_barrier(0);
    __builtin_amdgcn_s_barrier();
    LOADFRAGS(p0, Ae0, Ae1, Be0, Be1);
    PIN(Ae0); PIN(Ae1); PIN(Be0); PIN(Be1);
    asm volatile("s_waitcnt lgkmcnt(0)" ::: "memory");
    __builtin_amdgcn_sched_barrier(0);

#define BODY(CURA0, CURA1, CURB0, CURB1, NXTA0, NXTA1, NXTB0, NXTB1, S) do {  \
    STAGE(p2, (S) + 2);                                                        \
    __builtin_amdgcn_sched_barrier(0);                                         \
    asm volatile("s_waitcnt vmcnt(6)" ::: "memory");                           \
    __builtin_amdgcn_sched_barrier(0);                                         \
    __builtin_amdgcn_s_barrier();                                              \
    LOADFRAGS(p1, NXTA0, NXTA1, NXTB0, NXTB1);                                 \
    PIN(NXTA0); PIN(NXTA1); PIN(NXTB0); PIN(NXTB1);                            \
    __builtin_amdgcn_sched_barrier(0);                                         \
    __builtin_amdgcn_s_setprio(1);                                             \
    MFMA32(CURA0, CURA1, CURB0, CURB1);                                        \
    __builtin_amdgcn_s_setprio(0);                                             \
    asm volatile("s_waitcnt lgkmcnt(0)" ::: "memory");                         \
    __builtin_amdgcn_sched_barrier(0);                                         \
    { char* _t = p0; p0 = p1; p1 = p2; p2 = _t; }                              \
} while (0)

    for (int t = 0; t < 15; ++t) {
        const int s = 2 * t;
        BODY(Ae0, Ae1, Be0, Be1, Ao0, Ao1, Bo0, Bo1, s);
        BODY(Ao0, Ao1, Bo0, Bo1, Ae0, Ae1, Be0, Be1, s + 1);
    }
    asm volatile("s_waitcnt vmcnt(0)" ::: "memory");
    __builtin_amdgcn_sched_barrier(0);
    __builtin_amdgcn_s_barrier();
    LOADFRAGS(p1, Ao0, Ao1, Bo0, Bo1);
    PIN(Ao0); PIN(Ao1); PIN(Bo0); PIN(Bo1);
    __builtin_amdgcn_sched_barrier(0);
    __builtin_amdgcn_s_setprio(1);
    MFMA32(Ae0, Ae1, Be0, Be1);
    __builtin_amdgcn_s_setprio(0);
    asm volatile("s_waitcnt lgkmcnt(0)" ::: "memory");
    __builtin_amdgcn_sched_barrier(0);
    MFMA32(Ao0, Ao1, Bo0, Bo1);

    #pragma unroll
    for (int j = 0; j < 4; ++j) {
        int col = tileN + wn * 64 + j * 16 + (l & 15);
        float bj = bias[col];
        #pragma unroll
        for (int i = 0; i < 4; ++i) {
            int rw = tileM + wm * 64 + i * 16 + (l >> 4) * 4;
            #pragma unroll
            for (int r = 0; r < 4; ++r)
                C[(size_t)(rw + r) * DIM + col] = acc[i][j][r] + bj;
        }
    }
}

extern "C" void kernel_launch(void* const* d_in, const int* in_sizes, int n_in,
                              void* d_out, int out_size, void* d_ws, size_t ws_size,
                              hipStream_t stream) {
    const float* x     = (const float*)d_in[0];
    const int*   rows0 = (const int*)  d_in[1];
    const int*   cols0 = (const int*)  d_in[2];
    const float* vals0 = (const float*)d_in[3];
    const int*   rows1 = (const int*)  d_in[4];
    const int*   cols1 = (const int*)  d_in[5];
    const float* vals1 = (const float*)d_in[6];
    const int*   rows2 = (const int*)  d_in[7];
    const int*   cols2 = (const int*)  d_in[8];
    const float* vals2 = (const float*)d_in[9];
    const float* bias  = (const float*)d_in[10];
    float* out = (float*)d_out;

    char* ws = (char*)d_ws;
    unsigned short* Mc = (unsigned short*)ws;                 // 8 MB
    unsigned short* Xb = (unsigned short*)(ws + 8388608);     // 16 MB
    int*  cnt = (int*)(ws + 25165824);             // 3*2048 ints
    int2* bkt = (int2*)(cnt + 3 * DIM);            // 3*2048*BCAP int2 (~1.97 MB)

    zero_kernel<<<(3 * DIM + NT - 1) / NT, NT, 0, stream>>>(cnt);
    scatterd_kernel<<<3 * NNZc / NT, NT, 0, stream>>>(rows0, cols0, vals0,
                                                      rows1, cols1, vals1,
                                                      rows2, cols2, vals2,
                                                      cnt, bkt);
    mcxconv_kernel<<<DIM / RPB, NT, 0, stream>>>(x, Xb, cnt, bkt, Mc);

    (void)hipFuncSetAttribute((const void*)gemm8,
                              hipFuncAttributeMaxDynamicSharedMemorySize, GEMM_LDS);
    gemm8<<<256, 512, GEMM_LDS, stream>>>(Xb, Mc, bias, out);
}

// Round 19
// 63.091 us; speedup vs baseline: 7.7500x; 1.0256x over previous
//
#include <hip/hip_runtime.h>

// SparseProductLayer:  out = x @ (M0*M1*M2)^T + bias
// Pipeline (4 launches): zero counters -> direct padded-bucket scatter (int2)
// -> [mcbuild+xconv fused, RPB=1, 2048 blocks] -> MFMA GEMM (r14 core minus
// setprio: BM=128,BN=256,BK=64, 3-slot ring, vmcnt(6), pinned frag dbuf,
// chunk^row&7 swizzle, XCD-chunked block swizzle).

#define BATCH 4096
#define DIM   2048
#define NNZc  16384
#define NT    256
#define BCAP  40      // bucket capacity per row (Poisson lambda=8 -> P(>40)~0)

typedef short bf16x8 __attribute__((ext_vector_type(8)));
typedef float f32x4  __attribute__((ext_vector_type(4)));

__device__ __forceinline__ unsigned short f2bf(float f) {
    unsigned u = __float_as_uint(f);
    unsigned r = (u + 0x7fffu + ((u >> 16) & 1u)) >> 16;   // RNE
    return (unsigned short)r;
}

__device__ __forceinline__ void gload16(const void* g, void* l) {
    __builtin_amdgcn_global_load_lds((const __attribute__((address_space(1))) void*)g,
                                     (__attribute__((address_space(3))) void*)l, 16, 0, 0);
}

// ---- zero the 3*2048 counters ----
__global__ void zero_kernel(int* __restrict__ p) {
    int i = blockIdx.x * NT + threadIdx.x;
    if (i < 3 * DIM) p[i] = 0;
}

// ---- direct scatter into padded row buckets, (col,val) packed as int2 ----
__global__ void scatterd_kernel(const int* __restrict__ rows0, const int* __restrict__ cols0,
                                const float* __restrict__ vals0,
                                const int* __restrict__ rows1, const int* __restrict__ cols1,
                                const float* __restrict__ vals1,
                                const int* __restrict__ rows2, const int* __restrict__ cols2,
                                const float* __restrict__ vals2,
                                int* __restrict__ cnt, int2* __restrict__ bkt) {
    int e = blockIdx.x * NT + threadIdx.x;          // 0 .. 3*NNZ
    int m = e >> 14, i = e & (NNZc - 1);
    const int*   rp = (m == 0) ? rows0 : (m == 1) ? rows1 : rows2;
    const int*   cp = (m == 0) ? cols0 : (m == 1) ? cols1 : cols2;
    const float* vp = (m == 0) ? vals0 : (m == 1) ? vals1 : vals2;
    int r = rp[i];
    int slot = atomicAdd(&cnt[m * DIM + r], 1);
    if (slot < BCAP)
        bkt[(m * DIM + r) * BCAP + slot] = make_int2(cp[i], __float_as_int(vp[i]));
}

// ---- fused mcbuild + xconv: 2048 blocks, 1 Mc row each, 2-D expansion ----
#define PCAP 1024
__global__ __launch_bounds__(NT) void mcxconv_kernel(
        const float* __restrict__ x, unsigned short* __restrict__ Xb,
        const int* __restrict__ cnt, const int2* __restrict__ bkt,
        unsigned short* __restrict__ Mc) {
    // ---- xconv: this block's 2 chunks of 2048 elements ----
    #pragma unroll
    for (int u = 0; u < 2; ++u) {
        size_t i = (((size_t)blockIdx.x * 2 + u) * NT + threadIdx.x) * 8;
        float4 a = *(const float4*)(x + i);
        float4 b = *(const float4*)(x + i + 4);
        unsigned short o[8] = {f2bf(a.x), f2bf(a.y), f2bf(a.z), f2bf(a.w),
                               f2bf(b.x), f2bf(b.y), f2bf(b.z), f2bf(b.w)};
        *(ulonglong2*)(Xb + i) = *(ulonglong2*)o;
    }

    // ---- mcbuild: row b via 3-level bucket tree walk in LDS ----
    __shared__ float acc[DIM];        // 8 KB
    __shared__ int   pk[PCAP];        // 4 KB
    __shared__ float pw[PCAP];        // 4 KB
    __shared__ int   sc0[BCAP];
    __shared__ float sv0[BCAP];
    __shared__ int   npairs;

    const int tid = threadIdx.x;
    const int row = blockIdx.x;

    f32x4* az = (f32x4*)acc;
    #pragma unroll
    for (int j = tid; j < DIM / 4; j += NT) az[j] = (f32x4){0.f, 0.f, 0.f, 0.f};
    if (tid == 0) npairs = 0;
    __syncthreads();

    // expansion: thread (i0 = tid>>4, jj = tid&15) covers 16 x 16 (i,j) pairs
    const int i0 = tid >> 4, jj = tid & 15;
    {
        int n0 = min(cnt[row], BCAP);
        if (tid < n0) {
            int2 e0 = bkt[row * BCAP + tid];
            sc0[tid] = e0.x; sv0[tid] = __int_as_float(e0.y);
        }
        __syncthreads();
        for (int ib = 0; ib < n0; ib += 16) {
            int i = ib + i0;
            if (i < n0) {
                int   c0v = sc0[i];
                float v0  = sv0[i];
                int n1 = min(cnt[DIM + c0v], BCAP);
                for (int j = jj; j < n1; j += 16) {
                    int2  e1 = bkt[(DIM + c0v) * BCAP + j];
                    float w  = v0 * __int_as_float(e1.y);
                    int slot = atomicAdd(&npairs, 1);
                    if (slot < PCAP) { pk[slot] = e1.x; pw[slot] = w; }
                    else {  // overflow fallback (statistically never)
                        int n2 = min(cnt[2 * DIM + e1.x], BCAP);
                        const int2* b2 = bkt + (2 * DIM + e1.x) * BCAP;
                        for (int q = 0; q < n2; ++q) {
                            int2 e2 = b2[q];
                            atomicAdd(&acc[e2.x], w * __int_as_float(e2.y));
                        }
                    }
                }
            }
        }
        __syncthreads();
    }

    int np = min(npairs, PCAP);
    for (int p = tid; p < np; p += NT) {
        int   c1 = pk[p];
        float w  = pw[p];
        int n2 = min(cnt[2 * DIM + c1], BCAP);
        const int2* b2 = bkt + (2 * DIM + c1) * BCAP;
        for (int q = 0; q < n2; ++q) {
            int2 e2 = b2[q];
            atomicAdd(&acc[e2.x], w * __int_as_float(e2.y));
        }
    }
    __syncthreads();

    {
        unsigned short o[8];
        #pragma unroll
        for (int jj2 = 0; jj2 < 8; ++jj2) o[jj2] = f2bf(acc[tid * 8 + jj2]);
        *(ulonglong2*)(Mc + (size_t)row * DIM + tid * 8) = *(ulonglong2*)o;
    }
}

// ---- GEMM: C = Xb(4096x2048) @ Mc^T + bias (r14 core, setprio removed) ----
#define BM 128
#define BN 256
#define BK 64
#define NS (DIM / BK)                   // 32
#define A_SL (BM * BK * 2)              // 16384
#define B_SL (BN * BK * 2)              // 32768
#define SLOT (A_SL + B_SL)              // 49152
#define GEMM_LDS (3 * SLOT)             // 147456

__global__ __launch_bounds__(512, 2) void gemm8(
        const unsigned short* __restrict__ A,   // Xb [4096][2048]
        const unsigned short* __restrict__ Bm,  // Mc [2048][2048]
        const float* __restrict__ bias,
        float* __restrict__ C) {
    extern __shared__ char smem[];
    const int tid = threadIdx.x;
    const int l = tid & 63, w = tid >> 6;
    const int wm = w & 1, wn = w >> 1;          // 2M x 4N wave grid, tile 64x64

    // XCD-chunked swizzle: xcd k=(bid&7) owns an 8y x 4x region
    const int bid = blockIdx.x;
    const int k = bid & 7, c = bid >> 3;
    const int tileM = ((k >> 1) * 8 + (c >> 2)) * BM;
    const int tileN = ((k & 1) * 4 + (c & 3)) * BN;

    const int r8   = l >> 3;
    const int clog = (l & 7) ^ r8;
    const unsigned short* aS0 = A  + (size_t)(tileM + 8 * w + r8) * DIM + clog * 8;
    const unsigned short* aS1 = aS0 + (size_t)64 * DIM;
    const unsigned short* bS0 = Bm + (size_t)(tileN + 32 * w + r8) * DIM + clog * 8;

#define STAGE(z, s) do {                                                   \
    gload16(aS0 +                (size_t)(s) * BK, (z) + w * 1024);        \
    gload16(aS1 +                (size_t)(s) * BK, (z) + 8192 + w * 1024); \
    gload16(bS0 +                (size_t)(s) * BK, (z) + A_SL + w * 4096);        \
    gload16(bS0 +  8 * DIM +     (size_t)(s) * BK, (z) + A_SL + w * 4096 + 1024); \
    gload16(bS0 + 16 * DIM +     (size_t)(s) * BK, (z) + A_SL + w * 4096 + 2048); \
    gload16(bS0 + 24 * DIM +     (size_t)(s) * BK, (z) + A_SL + w * 4096 + 3072); \
} while (0)

    const int rbyte = (l & 15) * 128;
    const int c0 = (((l >> 4)    ) ^ (l & 7)) * 16;   // ks=0
    const int c1 = (((l >> 4) + 4) ^ (l & 7)) * 16;   // ks=1

#define LOADFRAGS(z, A0, A1, B0, B1) do {                            \
    const char* _ab = (z) + wm * 8192 + rbyte;                       \
    A0[0] = *(const bf16x8*)(_ab + 0 * 2048 + c0);                   \
    A1[0] = *(const bf16x8*)(_ab + 0 * 2048 + c1);                   \
    A0[1] = *(const bf16x8*)(_ab + 1 * 2048 + c0);                   \
    A1[1] = *(const bf16x8*)(_ab + 1 * 2048 + c1);                   \
    A0[2] = *(const bf16x8*)(_ab + 2 * 2048 + c0);                   \
    A1[2] = *(const bf16x8*)(_ab + 2 * 2048 + c1);                   \
    A0[3] = *(const bf16x8*)(_ab + 3 * 2048 + c0);                   \
    A1[3] = *(const bf16x8*)(_ab + 3 * 2048 + c1);                   \
    const char* _bb = (z) + A_SL + wn * 8192 + rbyte;                \
    B0[0] = *(const bf16x8*)(_bb + 0 * 2048 + c0);                   \
    B1[0] = *(const bf16x8*)(_bb + 0 * 2048 + c1);                   \
    B0[1] = *(const bf16x8*)(_bb + 1 * 2048 + c0);                   \
    B1[1] = *(const bf16x8*)(_bb + 1 * 2048 + c1);                   \
    B0[2] = *(const bf16x8*)(_bb + 2 * 2048 + c0);                   \
    B1[2] = *(const bf16x8*)(_bb + 2 * 2048 + c1);                   \
    B0[3] = *(const bf16x8*)(_bb + 3 * 2048 + c0);                   \
    B1[3] = *(const bf16x8*)(_bb + 3 * 2048 + c1);                   \
} while (0)

#define PIN(X) asm volatile("" : "+v"(X[0]), "+v"(X[1]), "+v"(X[2]), "+v"(X[3]))

#define MFMA32(A0, A1, B0, B1) do {                                                    \
    _Pragma("unroll")                                                                  \
    for (int _q = 0; _q < 4; ++_q)                                                     \
        _Pragma("unroll")                                                              \
        for (int _j = 0; _j < 4; ++_j) {                                               \
            acc[_q][_j] = __builtin_amdgcn_mfma_f32_16x16x32_bf16(A0[_q], B0[_j],      \
                                                                  acc[_q][_j], 0,0,0); \
            acc[_q][_j] = __builtin_amdgcn_mfma_f32_16x16x32_bf16(A1[_q], B1[_j],      \
                                                                  acc[_q][_j], 0,0,0); \
        }                                                                              \
} while (0)

    bf16x8 Ae0[4], Ae1[4], Be0[4], Be1[4];
    bf16x8 Ao0[4], Ao1[4], Bo0[4], Bo1[4];
    f32x4 acc[4][4] = {};

    char* p0 = smem;
    char* p1 = smem + SLOT;
    char* p2 = smem + 2 * SLOT;

    STAGE(p0, 0);
    STAGE(p1, 1);
    asm volatile("s_waitcnt vmcnt(6)" ::: "memory");
    __builtin_amdgcn_sched_barrier(0);
    __builtin_amdgcn_s_barrier();
    LOADFRAGS(p0, Ae0, Ae1, Be0, Be1);
    PIN(Ae0); PIN(Ae1); PIN(Be0); PIN(Be1);
    asm volatile("s_waitcnt lgkmcnt(0)" ::: "memory");
    __builtin_amdgcn_sched_barrier(0);

#define BODY(CURA0, CURA1, CURB0, CURB1, NXTA0, NXTA1, NXTB0, NXTB1, S) do {  \
    STAGE(p2, (S) + 2);                                                        \
    __builtin_amdgcn_sched_barrier(0);                                         \
    asm volatile("s_waitcnt vmcnt(6)" ::: "memory");                           \
    __builtin_amdgcn_sched_barrier(0);                                         \
    __builtin_amdgcn_s_barrier();                                              \
    LOADFRAGS(p1, NXTA0, NXTA1, NXTB0, NXTB1);                                 \
    PIN(NXTA0); PIN(NXTA1); PIN(NXTB0); PIN(NXTB1);                            \
    __builtin_amdgcn_sched_barrier(0);                                         \
    MFMA32(CURA0, CURA1, CURB0, CURB1);                                        \
    asm volatile("s_waitcnt lgkmcnt(0)" ::: "memory");                         \
    __builtin_amdgcn_sched_barrier(0);                                         \
    { char* _t = p0; p0 = p1; p1 = p2; p2 = _t; }                              \
} while (0)

    for (int t = 0; t < 15; ++t) {
        const int s = 2 * t;
        BODY(Ae0, Ae1, Be0, Be1, Ao0, Ao1, Bo0, Bo1, s);
        BODY(Ao0, Ao1, Bo0, Bo1, Ae0, Ae1, Be0, Be1, s + 1);
    }
    asm volatile("s_waitcnt vmcnt(0)" ::: "memory");
    __builtin_amdgcn_sched_barrier(0);
    __builtin_amdgcn_s_barrier();
    LOADFRAGS(p1, Ao0, Ao1, Bo0, Bo1);
    PIN(Ao0); PIN(Ao1); PIN(Bo0); PIN(Bo1);
    __builtin_amdgcn_sched_barrier(0);
    MFMA32(Ae0, Ae1, Be0, Be1);
    asm volatile("s_waitcnt lgkmcnt(0)" ::: "memory");
    __builtin_amdgcn_sched_barrier(0);
    MFMA32(Ao0, Ao1, Bo0, Bo1);

    #pragma unroll
    for (int j = 0; j < 4; ++j) {
        int col = tileN + wn * 64 + j * 16 + (l & 15);
        float bj = bias[col];
        #pragma unroll
        for (int i = 0; i < 4; ++i) {
            int rw = tileM + wm * 64 + i * 16 + (l >> 4) * 4;
            #pragma unroll
            for (int r = 0; r < 4; ++r)
                C[(size_t)(rw + r) * DIM + col] = acc[i][j][r] + bj;
        }
    }
}

extern "C" void kernel_launch(void* const* d_in, const int* in_sizes, int n_in,
                              void* d_out, int out_size, void* d_ws, size_t ws_size,
                              hipStream_t stream) {
    const float* x     = (const float*)d_in[0];
    const int*   rows0 = (const int*)  d_in[1];
    const int*   cols0 = (const int*)  d_in[2];
    const float* vals0 = (const float*)d_in[3];
    const int*   rows1 = (const int*)  d_in[4];
    const int*   cols1 = (const int*)  d_in[5];
    const float* vals1 = (const float*)d_in[6];
    const int*   rows2 = (const int*)  d_in[7];
    const int*   cols2 = (const int*)  d_in[8];
    const float* vals2 = (const float*)d_in[9];
    const float* bias  = (const float*)d_in[10];
    float* out = (float*)d_out;

    char* ws = (char*)d_ws;
    unsigned short* Mc = (unsigned short*)ws;                 // 8 MB
    unsigned short* Xb = (unsigned short*)(ws + 8388608);     // 16 MB
    int*  cnt = (int*)(ws + 25165824);             // 3*2048 ints
    int2* bkt = (int2*)(cnt + 3 * DIM);            // 3*2048*BCAP int2 (~1.97 MB)

    zero_kernel<<<(3 * DIM + NT - 1) / NT, NT, 0, stream>>>(cnt);
    scatterd_kernel<<<3 * NNZc / NT, NT, 0, stream>>>(rows0, cols0, vals0,
                                                      rows1, cols1, vals1,
                                                      rows2, cols2, vals2,
                                                      cnt, bkt);
    mcxconv_kernel<<<DIM, NT, 0, stream>>>(x, Xb, cnt, bkt, Mc);

    (void)hipFuncSetAttribute((const void*)gemm8,
                              hipFuncAttributeMaxDynamicSharedMemorySize, GEMM_LDS);
    gemm8<<<256, 512, GEMM_LDS, stream>>>(Xb, Mc, bias, out);
}